// Round 8
// baseline (234.791 us; speedup 1.0000x reference)
//
#include <hip/hip_runtime.h>
#include <math.h>

// Problem constants (fixed by the reference)
#define NSEG 32
#define T_DIM 8
#define F_DIM 32
#define P_DIM 8
#define TF 256           // T_DIM * F_DIM
#define OUT_PER_SEG 2048 // T*P*F
#define EPS_DENOM 1e-16f

#define CHUNK 256
#define K2_THREADS 256
#define NPW (CHUNK / 4)   // 4 waves per block, 64 nodes each
#define MAX_LDS_TAGS 1024

// Tiny MLP: h = elu(pos @ W1 + b1) @ W2 + b2  (per node, P=8 outputs)
__device__ __forceinline__ void compute_h(
    float h[P_DIM], const float* __restrict__ pos, int n,
    const float* __restrict__ W1, const float* __restrict__ b1,
    const float* __restrict__ W2, const float* __restrict__ b2) {
  float p0 = pos[3 * n + 0];
  float p1 = pos[3 * n + 1];
  float p2 = pos[3 * n + 2];
  float a[P_DIM];
#pragma unroll
  for (int p = 0; p < P_DIM; p++) {
    float v = b1[p] + p0 * W1[0 * P_DIM + p] + p1 * W1[1 * P_DIM + p] + p2 * W1[2 * P_DIM + p];
    a[p] = v > 0.f ? v : (__expf(v) - 1.f);  // ELU, alpha=1
  }
#pragma unroll
  for (int p = 0; p < P_DIM; p++) {
    float v = b2[p];
#pragma unroll
    for (int j = 0; j < P_DIM; j++) v += a[j] * W2[j * P_DIM + p];
    h[p] = v;
  }
}

// Kernel 0: zero the output + the tiny atomic exp-sum array (both only touched
// by the never-in-practice middle-run fallback before reduce reads them).
__global__ __launch_bounds__(256) void zero_kernel(float* __restrict__ out, int nf,
                                                   float* __restrict__ esum_a) {
  int i = (blockIdx.x * 256 + threadIdx.x) * 8;
  if (i + 8 <= nf) {
    float4* o = reinterpret_cast<float4*>(out + i);
    float4 z = make_float4(0.f, 0.f, 0.f, 0.f);
    o[0] = z;
    o[1] = z;
  }
  if (blockIdx.x == 0 && threadIdx.x < NSEG * P_DIM) esum_a[threadIdx.x] = 0.f;
}

// per-node FMA: acc[p] (float4 over f) += e[p] * x[n, t, f..f+3]
#define FMA_NODE(ii, xv) do {                                                  \
    const float4* _wr = reinterpret_cast<const float4*>(&wbuf[(ii)][0]);       \
    float4 _wa = _wr[0], _wb = _wr[1];                                         \
    acc[0].x += _wa.x*(xv).x; acc[0].y += _wa.x*(xv).y;                        \
    acc[0].z += _wa.x*(xv).z; acc[0].w += _wa.x*(xv).w;                        \
    acc[1].x += _wa.y*(xv).x; acc[1].y += _wa.y*(xv).y;                        \
    acc[1].z += _wa.y*(xv).z; acc[1].w += _wa.y*(xv).w;                        \
    acc[2].x += _wa.z*(xv).x; acc[2].y += _wa.z*(xv).y;                        \
    acc[2].z += _wa.z*(xv).z; acc[2].w += _wa.z*(xv).w;                        \
    acc[3].x += _wa.w*(xv).x; acc[3].y += _wa.w*(xv).y;                        \
    acc[3].z += _wa.w*(xv).z; acc[3].w += _wa.w*(xv).w;                        \
    acc[4].x += _wb.x*(xv).x; acc[4].y += _wb.x*(xv).y;                        \
    acc[4].z += _wb.x*(xv).z; acc[4].w += _wb.x*(xv).w;                        \
    acc[5].x += _wb.y*(xv).x; acc[5].y += _wb.y*(xv).y;                        \
    acc[5].z += _wb.y*(xv).z; acc[5].w += _wb.y*(xv).w;                        \
    acc[6].x += _wb.z*(xv).x; acc[6].y += _wb.z*(xv).y;                        \
    acc[6].z += _wb.z*(xv).z; acc[6].w += _wb.z*(xv).w;                        \
    acc[7].x += _wb.w*(xv).x; acc[7].y += _wb.w*(xv).y;                        \
    acc[7].z += _wb.w*(xv).z; acc[7].w += _wb.w*(xv).w;                        \
  } while (0)

// atomic fallback for a middle run (complete segment inside one 256-chunk;
// impossible for this data: min segment ~2900 nodes)
__device__ __forceinline__ void flush_atomic(float* __restrict__ out, int sg, int c,
                                             float4 acc[P_DIM]) {
  float* o = out + (size_t)sg * OUT_PER_SEG + (c >> 3) * (P_DIM * F_DIM) + (c & 7) * 4;
#pragma unroll
  for (int p = 0; p < P_DIM; p++) {
    float* op = o + p * F_DIM;
    unsafeAtomicAdd(op + 0, acc[p].x);
    unsafeAtomicAdd(op + 1, acc[p].y);
    unsafeAtomicAdd(op + 2, acc[p].z);
    unsafeAtomicAdd(op + 3, acc[p].w);
    acc[p] = make_float4(0.f, 0.f, 0.f, 0.f);
  }
}

// Kernel 1: block = 256 consecutive nodes, UNNORMALIZED accumulation of
// exp(h[n,p]) * x[n,t,f]. Fast path is byte-identical to the r3/r7 kernel.
// NEW vs r7: phase A also block-reduces per-run exp-sums into esum[slot][8]
// (so reduce_kernel needs no pos pass / binary search), and boundary blocks
// (~15 of 391) store BOTH runs as tagged slots via a two-pass masked stream
// (unconditional batch-8 loads, predicated FMA, single acc set) -- zero
// atomics on any practical path.
__global__ __launch_bounds__(K2_THREADS) void accum_kernel(
    const float* __restrict__ x, const float* __restrict__ pos,
    const int* __restrict__ seg,
    const float* __restrict__ W1, const float* __restrict__ b1,
    const float* __restrict__ W2, const float* __restrict__ b2,
    float* __restrict__ out, float* __restrict__ part,
    float* __restrict__ esum, float* __restrict__ esum_a,
    int* __restrict__ segtag, int N) {
  __shared__ __align__(16) float wbuf[CHUNK][P_DIM];   // 8 KB
  __shared__ int sbuf[CHUNK];                          // 1 KB
  __shared__ float4 facc[P_DIM][4][64];                // 32 KB, [p][group][col]
  __shared__ float ered[P_DIM][2][4];                  // exp-sum cross-wave

  int base = blockIdx.x * CHUNK;
  int cnt = N - base;
  if (cnt > CHUNK) cnt = CHUNK;
  int tid = threadIdx.x;

  // Phase A: e[node][p] = exp(h)
  float e[P_DIM];
  int sg_t = -1;
#pragma unroll
  for (int p = 0; p < P_DIM; p++) e[p] = 0.f;
  if (tid < cnt) {
    int n = base + tid;
    sg_t = seg[n];
    sbuf[tid] = sg_t;
    float h[P_DIM];
    compute_h(h, pos, n, W1, b1, W2, b2);
#pragma unroll
    for (int p = 0; p < P_DIM; p++) {
      e[p] = __expf(h[p]);
      wbuf[tid][p] = e[p];
    }
  }
  __syncthreads();

  int sA = sbuf[0];
  int sB = sbuf[cnt - 1];
  bool single = (sA == sB);
  int g = tid >> 6;
  int lane = tid & 63;

  // per-run exp-sum block reduction (slot 0 = run A, slot 1 = run B)
  {
    float vA[P_DIM];
#pragma unroll
    for (int p = 0; p < P_DIM; p++) vA[p] = (sg_t == sA) ? e[p] : 0.f;
#pragma unroll
    for (int off = 32; off >= 1; off >>= 1)
#pragma unroll
      for (int p = 0; p < P_DIM; p++) vA[p] += __shfl_down(vA[p], off, 64);
    if (lane == 0) {
#pragma unroll
      for (int p = 0; p < P_DIM; p++) ered[p][0][g] = vA[p];
    }
    if (!single) {
      float vB[P_DIM];
#pragma unroll
      for (int p = 0; p < P_DIM; p++) vB[p] = (sg_t == sB) ? e[p] : 0.f;
#pragma unroll
      for (int off = 32; off >= 1; off >>= 1)
#pragma unroll
        for (int p = 0; p < P_DIM; p++) vB[p] += __shfl_down(vB[p], off, 64);
      if (lane == 0) {
#pragma unroll
        for (int p = 0; p < P_DIM; p++) ered[p][1][g] = vB[p];
      }
      // middle-run nodes (~never): exp-sums via atomics
      if (sg_t >= 0 && sg_t != sA && sg_t != sB) {
#pragma unroll
        for (int p = 0; p < P_DIM; p++)
          unsafeAtomicAdd(&esum_a[sg_t * P_DIM + p], e[p]);
      }
    }
  }
  __syncthreads();
  if (tid < P_DIM) {
    esum[(size_t)(2 * blockIdx.x) * P_DIM + tid] =
        ered[tid][0][0] + ered[tid][0][1] + ered[tid][0][2] + ered[tid][0][3];
    if (!single)
      esum[(size_t)(2 * blockIdx.x + 1) * P_DIM + tid] =
          ered[tid][1][0] + ered[tid][1][1] + ered[tid][1][2] + ered[tid][1][3];
  }
  if (tid == 0) {
    segtag[2 * blockIdx.x] = sA;
    segtag[2 * blockIdx.x + 1] = single ? -1 : sB;
  }

  int c = lane;       // column: t = c>>3, f = (c&7)*4
  int i0 = g * NPW;
  int i1 = i0 + NPW;
  if (i1 > cnt) i1 = cnt;
  if (i0 > cnt) i0 = cnt;

  const float4* xp = reinterpret_cast<const float4*>(x) + (size_t)base * (TF / 4) + c;

  if (single) {
    float4 acc[P_DIM];
#pragma unroll
    for (int p = 0; p < P_DIM; p++) acc[p] = make_float4(0.f, 0.f, 0.f, 0.f);

    int i = i0;
    for (; i + 8 <= i1; i += 8) {
      float4 xv[8];
#pragma unroll
      for (int j = 0; j < 8; j++) xv[j] = xp[(size_t)(i + j) * (TF / 4)];
#pragma unroll
      for (int j = 0; j < 8; j++) FMA_NODE(i + j, xv[j]);
    }
    for (; i < i1; ++i) {
      float4 xv = xp[(size_t)i * (TF / 4)];
      FMA_NODE(i, xv);
    }

    // stash per-group accumulators, cross-wave reduce, store slot 2b
#pragma unroll
    for (int p = 0; p < P_DIM; p++) facc[p][g][c] = acc[p];
    __syncthreads();
    int t = tid >> 5;
    int p = (tid >> 2) & 7;
    int fb = tid & 3;
    int c0 = t * 8 + fb * 2;
    float4 A = facc[p][0][c0];
    float4 B = facc[p][0][c0 + 1];
#pragma unroll
    for (int gg = 1; gg < 4; gg++) {
      float4 a2 = facc[p][gg][c0];
      float4 b2v = facc[p][gg][c0 + 1];
      A.x += a2.x;  A.y += a2.y;  A.z += a2.z;  A.w += a2.w;
      B.x += b2v.x; B.y += b2v.y; B.z += b2v.z; B.w += b2v.w;
    }
    int off = t * (P_DIM * F_DIM) + p * F_DIM + fb * 8;
    float4* po = reinterpret_cast<float4*>(part + (size_t)(2 * blockIdx.x) * OUT_PER_SEG + off);
    po[0] = A;
    po[1] = B;
  } else {
    // boundary block: two masked passes (targets sA then sB), each stored to
    // its own tagged slot. Loads unconditional (batch-8, pipelined); FMA
    // predicated by the node's segment (uniform branch).
    for (int pass = 0; pass < 2; ++pass) {
      int target = pass ? sB : sA;
      float4 acc[P_DIM];
#pragma unroll
      for (int p = 0; p < P_DIM; p++) acc[p] = make_float4(0.f, 0.f, 0.f, 0.f);

      int i = i0;
      for (; i + 8 <= i1; i += 8) {
        float4 xv[8];
#pragma unroll
        for (int j = 0; j < 8; j++) xv[j] = xp[(size_t)(i + j) * (TF / 4)];
#pragma unroll
        for (int j = 0; j < 8; j++)
          if (sbuf[i + j] == target) FMA_NODE(i + j, xv[j]);
      }
      for (; i < i1; ++i) {
        if (sbuf[i] == target) {
          float4 xv = xp[(size_t)i * (TF / 4)];
          FMA_NODE(i, xv);
        }
      }

#pragma unroll
      for (int p = 0; p < P_DIM; p++) facc[p][g][c] = acc[p];
      __syncthreads();
      int t = tid >> 5;
      int p = (tid >> 2) & 7;
      int fb = tid & 3;
      int c0 = t * 8 + fb * 2;
      float4 A = facc[p][0][c0];
      float4 B = facc[p][0][c0 + 1];
#pragma unroll
      for (int gg = 1; gg < 4; gg++) {
        float4 a2 = facc[p][gg][c0];
        float4 b2v = facc[p][gg][c0 + 1];
        A.x += a2.x;  A.y += a2.y;  A.z += a2.z;  A.w += a2.w;
        B.x += b2v.x; B.y += b2v.y; B.z += b2v.z; B.w += b2v.w;
      }
      int off = t * (P_DIM * F_DIM) + p * F_DIM + fb * 8;
      float4* po = reinterpret_cast<float4*>(
          part + (size_t)(2 * blockIdx.x + pass) * OUT_PER_SEG + off);
      po[0] = A;
      po[1] = B;
      __syncthreads();  // facc reused by pass 1
    }

    // middle runs (~never): accumulate and flush via atomics
    {
      float4 acc[P_DIM];
#pragma unroll
      for (int p = 0; p < P_DIM; p++) acc[p] = make_float4(0.f, 0.f, 0.f, 0.f);
      int i = i0;
      while (i < i1) {
        int cur = sbuf[i];
        int j = i + 1;
        while (j < i1 && sbuf[j] == cur) j++;
        if (cur != sA && cur != sB) {
          for (int k = i; k < j; ++k) {
            float4 xv = xp[(size_t)k * (TF / 4)];
            FMA_NODE(k, xv);
          }
          flush_atomic(out, cur, c, acc);
        }
        i = j;
      }
    }
  }
}

// Kernel 2: one block per segment. No pos pass, no binary search: stages all
// slot tags in LDS, sums matching esum slots for the denominator, then
//   out = (out_atomic + sum of matching partial slots) * inv_den.
__global__ __launch_bounds__(256) void reduce_kernel(
    const int* __restrict__ segtag, const float* __restrict__ part,
    const float* __restrict__ esum, const float* __restrict__ esum_a,
    float* __restrict__ out, int nslot) {
  int s = blockIdx.x;
  int tid = threadIdx.x;

  __shared__ int stag[MAX_LDS_TAGS];
  int ns = nslot < MAX_LDS_TAGS ? nslot : MAX_LDS_TAGS;
  for (int i = tid; i < ns; i += 256) stag[i] = segtag[i];
  __syncthreads();

  // denominator: parallel over threads (p = tid&7, 32 slot-stride groups)
  __shared__ float dred[P_DIM][32];
  __shared__ float invd[P_DIM];
  {
    int p = tid & 7;
    int grp = tid >> 3;
    float ds = 0.f;
    for (int sl = grp; sl < ns; sl += 32)
      if (stag[sl] == s) ds += esum[(size_t)sl * P_DIM + p];
    for (int sl = ns + grp; sl < nslot; sl += 32)   // overflow range (unused)
      if (segtag[sl] == s) ds += esum[(size_t)sl * P_DIM + p];
    dred[p][grp] = ds;
  }
  __syncthreads();
  if (tid < P_DIM) {
    float ss = 0.f;
#pragma unroll
    for (int w = 0; w < 32; w++) ss += dred[tid][w];
    ss += esum_a[s * P_DIM + tid];
    invd[tid] = 1.f / (ss + EPS_DENOM);
  }
  __syncthreads();

  // output accumulation: scan LDS tags, add matching slots (each thread owns
  // 8 consecutive floats of the segment's 2048-float tile)
  int p = (tid >> 2) & 7;  // out layout: [t][p][f], tid*8 = t*256 + p*32 + fb*8
  float s0 = invd[p];

  float* o = out + (size_t)s * OUT_PER_SEG + tid * 8;
  float4 A = reinterpret_cast<float4*>(o)[0];  // middle-run atomics (~0)
  float4 B = reinterpret_cast<float4*>(o)[1];
  for (int sl = 0; sl < ns; sl++) {
    if (stag[sl] == s) {
      const float4* pp = reinterpret_cast<const float4*>(
          part + (size_t)sl * OUT_PER_SEG + tid * 8);
      float4 a2 = pp[0], b2v = pp[1];
      A.x += a2.x;  A.y += a2.y;  A.z += a2.z;  A.w += a2.w;
      B.x += b2v.x; B.y += b2v.y; B.z += b2v.z; B.w += b2v.w;
    }
  }
  for (int sl = ns; sl < nslot; sl++) {   // overflow range (unused)
    if (segtag[sl] == s) {
      const float4* pp = reinterpret_cast<const float4*>(
          part + (size_t)sl * OUT_PER_SEG + tid * 8);
      float4 a2 = pp[0], b2v = pp[1];
      A.x += a2.x;  A.y += a2.y;  A.z += a2.z;  A.w += a2.w;
      B.x += b2v.x; B.y += b2v.y; B.z += b2v.z; B.w += b2v.w;
    }
  }
  A.x *= s0; A.y *= s0; A.z *= s0; A.w *= s0;
  B.x *= s0; B.y *= s0; B.z *= s0; B.w *= s0;
  reinterpret_cast<float4*>(o)[0] = A;
  reinterpret_cast<float4*>(o)[1] = B;
}

extern "C" void kernel_launch(void* const* d_in, const int* in_sizes, int n_in,
                              void* d_out, int out_size, void* d_ws, size_t ws_size,
                              hipStream_t stream) {
  const float* pos = (const float*)d_in[0];
  const float* x   = (const float*)d_in[1];
  const int*   seg = (const int*)d_in[2];
  const float* W1  = (const float*)d_in[3];
  const float* b1  = (const float*)d_in[4];
  const float* W2  = (const float*)d_in[5];
  const float* b2  = (const float*)d_in[6];
  float* out = (float*)d_out;
  int N = in_sizes[2];
  int nblk = (N + CHUNK - 1) / CHUNK;
  int nslot = 2 * nblk;

  // workspace: segtag [nslot i32] | esum_a [32*8 f32] | esum [nslot*8 f32]
  //          | partials [nslot*2048 f32]
  char* ws = (char*)d_ws;
  size_t off_ea  = ((size_t)nslot * 4 + 255) & ~(size_t)255;
  size_t off_es  = (off_ea + NSEG * P_DIM * 4 + 255) & ~(size_t)255;
  size_t off_pt  = (off_es + (size_t)nslot * P_DIM * 4 + 255) & ~(size_t)255;
  int*   segtag = (int*)ws;
  float* esum_a = (float*)(ws + off_ea);
  float* esum   = (float*)(ws + off_es);
  float* part   = (float*)(ws + off_pt);

  int zblk = (out_size / 8 + 255) / 256;
  zero_kernel<<<zblk, 256, 0, stream>>>(out, out_size, esum_a);

  accum_kernel<<<nblk, K2_THREADS, 0, stream>>>(
      x, pos, seg, W1, b1, W2, b2, out, part, esum, esum_a, segtag, N);

  reduce_kernel<<<NSEG, 256, 0, stream>>>(
      segtag, part, esum, esum_a, out, nslot);
}

// Round 9
// 191.884 us; speedup vs baseline: 1.2236x; 1.2236x over previous
//
#include <hip/hip_runtime.h>
#include <math.h>

// Problem constants (fixed by the reference)
#define NSEG 32
#define T_DIM 8
#define F_DIM 32
#define P_DIM 8
#define TF 256           // T_DIM * F_DIM
#define OUT_PER_SEG 2048 // T*P*F
#define EPS_DENOM 1e-16f

#define CHUNK 256
#define K2_THREADS 256
#define NPW (CHUNK / 4)   // 4 waves per block, 64 nodes each

// Tiny MLP: h = elu(pos @ W1 + b1) @ W2 + b2  (per node, P=8 outputs)
__device__ __forceinline__ void compute_h(
    float h[P_DIM], const float* __restrict__ pos, int n,
    const float* __restrict__ W1, const float* __restrict__ b1,
    const float* __restrict__ W2, const float* __restrict__ b2) {
  float p0 = pos[3 * n + 0];
  float p1 = pos[3 * n + 1];
  float p2 = pos[3 * n + 2];
  float a[P_DIM];
#pragma unroll
  for (int p = 0; p < P_DIM; p++) {
    float v = b1[p] + p0 * W1[0 * P_DIM + p] + p1 * W1[1 * P_DIM + p] + p2 * W1[2 * P_DIM + p];
    a[p] = v > 0.f ? v : (__expf(v) - 1.f);  // ELU, alpha=1
  }
#pragma unroll
  for (int p = 0; p < P_DIM; p++) {
    float v = b2[p];
#pragma unroll
    for (int j = 0; j < P_DIM; j++) v += a[j] * W2[j * P_DIM + p];
    h[p] = v;
  }
}

// Kernel 0: zero the output (boundary-block atomics land in it before reduce).
__global__ __launch_bounds__(256) void zero_kernel(float* __restrict__ out, int nf) {
  int i = (blockIdx.x * 256 + threadIdx.x) * 8;
  if (i + 8 <= nf) {
    float4* o = reinterpret_cast<float4*>(out + i);
    float4 z = make_float4(0.f, 0.f, 0.f, 0.f);
    o[0] = z;
    o[1] = z;
  }
}

// per-node FMA: acc[p] (float4 over f) += e[p] * x[n, t, f..f+3]
#define FMA_NODE(ii, xv) do {                                                  \
    const float4* _wr = reinterpret_cast<const float4*>(&wbuf[(ii)][0]);       \
    float4 _wa = _wr[0], _wb = _wr[1];                                         \
    acc[0].x += _wa.x*(xv).x; acc[0].y += _wa.x*(xv).y;                        \
    acc[0].z += _wa.x*(xv).z; acc[0].w += _wa.x*(xv).w;                        \
    acc[1].x += _wa.y*(xv).x; acc[1].y += _wa.y*(xv).y;                        \
    acc[1].z += _wa.y*(xv).z; acc[1].w += _wa.y*(xv).w;                        \
    acc[2].x += _wa.z*(xv).x; acc[2].y += _wa.z*(xv).y;                        \
    acc[2].z += _wa.z*(xv).z; acc[2].w += _wa.z*(xv).w;                        \
    acc[3].x += _wa.w*(xv).x; acc[3].y += _wa.w*(xv).y;                        \
    acc[3].z += _wa.w*(xv).z; acc[3].w += _wa.w*(xv).w;                        \
    acc[4].x += _wb.x*(xv).x; acc[4].y += _wb.x*(xv).y;                        \
    acc[4].z += _wb.x*(xv).z; acc[4].w += _wb.x*(xv).w;                        \
    acc[5].x += _wb.y*(xv).x; acc[5].y += _wb.y*(xv).y;                        \
    acc[5].z += _wb.y*(xv).z; acc[5].w += _wb.y*(xv).w;                        \
    acc[6].x += _wb.z*(xv).x; acc[6].y += _wb.z*(xv).y;                        \
    acc[6].z += _wb.z*(xv).z; acc[6].w += _wb.z*(xv).w;                        \
    acc[7].x += _wb.w*(xv).x; acc[7].y += _wb.w*(xv).y;                        \
    acc[7].z += _wb.w*(xv).z; acc[7].w += _wb.w*(xv).w;                        \
  } while (0)

// async DMA one node-row (64 lanes x float4 = 1 KB) into this wave's LDS slot.
// global src is per-lane; LDS dest is wave-uniform base (+ lane*16 by HW).
#define GLL_NODE(node, slot)                                                   \
  __builtin_amdgcn_global_load_lds(                                            \
      (const __attribute__((address_space(1))) void*)(xp + (size_t)(node) * 64),\
      (__attribute__((address_space(3))) void*)(xsl + (slot) * 64),            \
      16, 0, 0)

// flush accumulators via scalar f32 atomics (boundary blocks only; ~15 of 391)
__device__ __forceinline__ void flush_group(float* __restrict__ out, int sg, int c,
                                            float4 acc[P_DIM]) {
  float* o = out + (size_t)sg * OUT_PER_SEG + (c >> 3) * (P_DIM * F_DIM) + (c & 7) * 4;
#pragma unroll
  for (int p = 0; p < P_DIM; p++) {
    float* op = o + p * F_DIM;
    unsafeAtomicAdd(op + 0, acc[p].x);
    unsafeAtomicAdd(op + 1, acc[p].y);
    unsafeAtomicAdd(op + 2, acc[p].z);
    unsafeAtomicAdd(op + 3, acc[p].w);
    acc[p] = make_float4(0.f, 0.f, 0.f, 0.f);
  }
}

// Kernel 1: block = 256 consecutive nodes, UNNORMALIZED accumulation of
// exp(h[n,p]) * x[n,t,f] (denominator applied in reduce_kernel).
// Same structure as the 193us r3/r7 kernel; the ONE change is the uniform-wave
// streaming loop: global_load_lds DMA staging with counted vmcnt (8 x 1KB
// node-rows in flight per wave, independent of the register allocator --
// plain VGPR loads were compiler-rescheduled to a ~2-deep chain, which kept
// accum HBM-latency-bound at ~55us across r2-r7). The 32KB stage buffer is
// time-shared with the facc reduction tile (stream phase vs reduce phase,
// separated by an extra __syncthreads), keeping LDS at 41KB -> 3 blocks/CU,
// 12 waves x 8KB in flight = 96KB/CU >> ~24KB Little's-law requirement.
__global__ __launch_bounds__(K2_THREADS) void accum_kernel(
    const float* __restrict__ x, const float* __restrict__ pos,
    const int* __restrict__ seg,
    const float* __restrict__ W1, const float* __restrict__ b1,
    const float* __restrict__ W2, const float* __restrict__ b2,
    float* __restrict__ out, float* __restrict__ part,
    int* __restrict__ segtag, int N) {
  __shared__ __align__(16) float wbuf[CHUNK][P_DIM];   // 8 KB
  __shared__ int sbuf[CHUNK];                          // 1 KB
  // time-shared 32 KB: stream phase = xstage[wave][8 slots][64 cols] (float4)
  //                    reduce phase = facc[p][wave][col] (float4[8][4][64])
  __shared__ __align__(16) float4 shbuf[2048];

  int base = blockIdx.x * CHUNK;
  int cnt = N - base;
  if (cnt > CHUNK) cnt = CHUNK;
  int tid = threadIdx.x;

  // Phase A: e[node][p] = exp(h)
  if (tid < cnt) {
    int n = base + tid;
    sbuf[tid] = seg[n];
    float h[P_DIM];
    compute_h(h, pos, n, W1, b1, W2, b2);
#pragma unroll
    for (int p = 0; p < P_DIM; p++)
      wbuf[tid][p] = __expf(h[p]);
  }
  __syncthreads();

  int c = tid & 63;   // column: t = c>>3, f = (c&7)*4
  int g = tid >> 6;   // wave group, owns nodes [g*64, g*64+64)
  int i0 = g * NPW;
  int i1 = i0 + NPW;
  if (i1 > cnt) i1 = cnt;
  if (i0 > cnt) i0 = cnt;

  const float4* xp = reinterpret_cast<const float4*>(x) + (size_t)base * (TF / 4) + c;

  float4 acc[P_DIM];
#pragma unroll
  for (int p = 0; p < P_DIM; p++) acc[p] = make_float4(0.f, 0.f, 0.f, 0.f);

  bool single = (sbuf[0] == sbuf[cnt - 1]);  // block-uniform
  if (tid == 0) segtag[blockIdx.x] = single ? sbuf[0] : -1;

  if (single) {
    if (i1 - i0 == NPW) {
      // full 64-node wave: DMA-staged stream, 8 node-rows in flight.
      float4* xsl = &shbuf[g * 512];  // this wave's 8-slot stage (8 KB)
      // prologue: issue 8 (slots 0..7 <- nodes i0..i0+7)
#pragma unroll
      for (int j = 0; j < 8; ++j) GLL_NODE(i0 + j, j);
      // steady state: consume 4, issue 4  (never drain vmcnt to 0)
#pragma unroll
      for (int q = 0; q < 14; ++q) {
        asm volatile("s_waitcnt vmcnt(4)" ::: "memory");
        __builtin_amdgcn_sched_barrier(0);
        int ss = (q & 1) * 4;          // slot base (quads alternate halves)
        int nb = i0 + q * 4;           // node base
#pragma unroll
        for (int j = 0; j < 4; ++j) {
          float4 xv = xsl[(ss + j) * 64 + c];
          FMA_NODE(nb + j, xv);
        }
#pragma unroll
        for (int j = 0; j < 4; ++j) GLL_NODE(i0 + (q + 2) * 4 + j, ss + j);
      }
      // epilogue: two remaining quads
      asm volatile("s_waitcnt vmcnt(4)" ::: "memory");
      __builtin_amdgcn_sched_barrier(0);
#pragma unroll
      for (int j = 0; j < 4; ++j) {
        float4 xv = xsl[(0 + j) * 64 + c];
        FMA_NODE(i0 + 56 + j, xv);
      }
      asm volatile("s_waitcnt vmcnt(0)" ::: "memory");
      __builtin_amdgcn_sched_barrier(0);
#pragma unroll
      for (int j = 0; j < 4; ++j) {
        float4 xv = xsl[(4 + j) * 64 + c];
        FMA_NODE(i0 + 60 + j, xv);
      }
    } else {
      // tail wave of the last block: plain loads
      int i = i0;
      for (; i + 8 <= i1; i += 8) {
        float4 xv[8];
#pragma unroll
        for (int j = 0; j < 8; j++) xv[j] = xp[(size_t)(i + j) * (TF / 4)];
#pragma unroll
        for (int j = 0; j < 8; j++) FMA_NODE(i + j, xv[j]);
      }
      for (; i < i1; ++i) {
        float4 xv = xp[(size_t)i * (TF / 4)];
        FMA_NODE(i, xv);
      }
    }

    // all waves' DMA consumed (each drained vmcnt(0)); xstage is dead.
    __syncthreads();
    // facc view of shbuf: [p][g][c] -> shbuf[p*256 + g*64 + c]
#pragma unroll
    for (int p = 0; p < P_DIM; p++) shbuf[p * 256 + g * 64 + c] = acc[p];
    __syncthreads();

    // all 256 threads: reduce the 4 groups; each thread owns 8 consecutive floats
    int t = tid >> 5;
    int p = (tid >> 2) & 7;
    int fb = tid & 3;
    int c0 = t * 8 + fb * 2;
    float4 A = shbuf[p * 256 + 0 * 64 + c0];
    float4 B = shbuf[p * 256 + 0 * 64 + c0 + 1];
#pragma unroll
    for (int gg = 1; gg < 4; gg++) {
      float4 a2 = shbuf[p * 256 + gg * 64 + c0];
      float4 b2v = shbuf[p * 256 + gg * 64 + c0 + 1];
      A.x += a2.x;  A.y += a2.y;  A.z += a2.z;  A.w += a2.w;
      B.x += b2v.x; B.y += b2v.y; B.z += b2v.z; B.w += b2v.w;
    }
    int off = t * (P_DIM * F_DIM) + p * F_DIM + fb * 8;
    float4* po = reinterpret_cast<float4*>(part + (size_t)blockIdx.x * OUT_PER_SEG + off);
    po[0] = A;
    po[1] = B;
  } else {
    // Slow path: chunk spans segment boundaries (~15 of 391 blocks).
    // Stream run-by-run, flush each run via atomics into out (unnormalized).
    int i = i0;
    while (i < i1) {
      int cur = sbuf[i];
      int j = i + 1;
      while (j < i1 && sbuf[j] == cur) j++;
      int k = i;
      for (; k + 4 <= j; k += 4) {
        float4 xv0 = xp[(size_t)(k + 0) * (TF / 4)];
        float4 xv1 = xp[(size_t)(k + 1) * (TF / 4)];
        float4 xv2 = xp[(size_t)(k + 2) * (TF / 4)];
        float4 xv3 = xp[(size_t)(k + 3) * (TF / 4)];
        FMA_NODE(k + 0, xv0);
        FMA_NODE(k + 1, xv1);
        FMA_NODE(k + 2, xv2);
        FMA_NODE(k + 3, xv3);
      }
      for (; k < j; ++k) {
        float4 xv = xp[(size_t)k * (TF / 4)];
        FMA_NODE(k, xv);
      }
      flush_group(out, cur, c, acc);
      i = j;
    }
  }
}

// Kernel 2: one block per segment. Computes the softmax denominator (sum of
// exp(h) over the segment's nodes), then
//   out = (out_atomic + sum of tagged partial slots) * inv_den.
__global__ __launch_bounds__(256) void reduce_kernel(
    const int* __restrict__ seg, const int* __restrict__ segtag,
    const float* __restrict__ part, const float* __restrict__ pos,
    const float* __restrict__ W1, const float* __restrict__ b1,
    const float* __restrict__ W2, const float* __restrict__ b2,
    float* __restrict__ out, int N) {
  int s = blockIdx.x;
  int tid = threadIdx.x;

  // bounds of segment s (uniform across threads)
  int lo = 0, hi = N;
  while (lo < hi) { int mid = (lo + hi) >> 1; if (seg[mid] < s) lo = mid + 1; else hi = mid; }
  int start = lo;
  lo = start; hi = N;
  while (lo < hi) { int mid = (lo + hi) >> 1; if (seg[mid] < s + 1) lo = mid + 1; else hi = mid; }
  int end = lo;
  if (start >= end) return;  // empty segment: out stays zero

  // denominator: sum of exp(h) over the segment's nodes
  float lsum[P_DIM];
#pragma unroll
  for (int p = 0; p < P_DIM; p++) lsum[p] = 0.f;
  for (int i = start + tid; i < end; i += 256) {
    float h[P_DIM];
    compute_h(h, pos, i, W1, b1, W2, b2);
#pragma unroll
    for (int p = 0; p < P_DIM; p++) lsum[p] += __expf(h[p]);
  }
#pragma unroll
  for (int off = 32; off >= 1; off >>= 1)
#pragma unroll
    for (int p = 0; p < P_DIM; p++)
      lsum[p] += __shfl_down(lsum[p], off, 64);

  __shared__ float wred[P_DIM][4];
  __shared__ float invd[P_DIM];
  int wid = tid >> 6, lane = tid & 63;
  if (lane == 0) {
#pragma unroll
    for (int p = 0; p < P_DIM; p++) wred[p][wid] = lsum[p];
  }
  __syncthreads();
  if (tid < P_DIM) {
    float ss = wred[tid][0] + wred[tid][1] + wred[tid][2] + wred[tid][3];
    invd[tid] = 1.f / (ss + EPS_DENOM);
  }
  __syncthreads();

  // combine tagged partials + boundary atomic contributions, scale, store
  int b0 = start / CHUNK;
  int b1i = (end - 1) / CHUNK;
  int p = (tid >> 2) & 7;  // out layout: [t][p][f], tid*8 = t*256 + p*32 + fb*8
  float s0 = invd[p];

  float* o = out + (size_t)s * OUT_PER_SEG + tid * 8;
  float4 A = reinterpret_cast<float4*>(o)[0];
  float4 B = reinterpret_cast<float4*>(o)[1];
  for (int b = b0; b <= b1i; b++) {
    if (segtag[b] == s) {
      const float4* pp = reinterpret_cast<const float4*>(
          part + (size_t)b * OUT_PER_SEG + tid * 8);
      float4 a2 = pp[0], b2v = pp[1];
      A.x += a2.x;  A.y += a2.y;  A.z += a2.z;  A.w += a2.w;
      B.x += b2v.x; B.y += b2v.y; B.z += b2v.z; B.w += b2v.w;
    }
  }
  A.x *= s0; A.y *= s0; A.z *= s0; A.w *= s0;
  B.x *= s0; B.y *= s0; B.z *= s0; B.w *= s0;
  reinterpret_cast<float4*>(o)[0] = A;
  reinterpret_cast<float4*>(o)[1] = B;
}

extern "C" void kernel_launch(void* const* d_in, const int* in_sizes, int n_in,
                              void* d_out, int out_size, void* d_ws, size_t ws_size,
                              hipStream_t stream) {
  const float* pos = (const float*)d_in[0];
  const float* x   = (const float*)d_in[1];
  const int*   seg = (const int*)d_in[2];
  const float* W1  = (const float*)d_in[3];
  const float* b1  = (const float*)d_in[4];
  const float* W2  = (const float*)d_in[5];
  const float* b2  = (const float*)d_in[6];
  float* out = (float*)d_out;
  int N = in_sizes[2];
  int nblk = (N + CHUNK - 1) / CHUNK;

  // workspace layout: segtag [nblk i32] | partials [nblk*2048 f32]
  char* ws = (char*)d_ws;
  size_t part_off = ((size_t)nblk * 4 + 255) & ~(size_t)255;
  int* segtag = (int*)ws;
  float* part = (float*)(ws + part_off);

  int zblk = (out_size / 8 + 255) / 256;
  zero_kernel<<<zblk, 256, 0, stream>>>(out, out_size);

  accum_kernel<<<nblk, K2_THREADS, 0, stream>>>(
      x, pos, seg, W1, b1, W2, b2, out, part, segtag, N);

  reduce_kernel<<<NSEG, 256, 0, stream>>>(
      seg, segtag, part, pos, W1, b1, W2, b2, out, N);
}